// Round 1
// baseline (459.113 us; speedup 1.0000x reference)
//
#include <hip/hip_runtime.h>

#define NSEQ 2048
#define DMODEL 1024
#define NHEAD 16
#define HDIM 64
#define NBATCH 4
#define MTOT 8192
#define ATT_SCALE 0.125f
#define LOG2E 1.4426950408889634f

typedef __bf16 bf16x8 __attribute__((ext_vector_type(8)));
typedef float f32x4 __attribute__((ext_vector_type(4)));
typedef unsigned short u16;
typedef unsigned int u32;

__device__ __forceinline__ u16 f2bf(float f) {
  u32 u = __builtin_bit_cast(u32, f);
  return (u16)((u + 0x7fffu + ((u >> 16) & 1u)) >> 16);
}

__device__ __forceinline__ void gload_lds16(const void* g, void* l) {
  __builtin_amdgcn_global_load_lds(
      (__attribute__((address_space(1))) const u32*)g,
      (__attribute__((address_space(3))) u32*)l, 16, 0, 0);
}

// ---------------- cast fp32 -> bf16 ----------------
__global__ __launch_bounds__(256) void cast_f32_bf16(const float* __restrict__ in,
                                                     u16* __restrict__ out, int n) {
  int i = (blockIdx.x * 256 + threadIdx.x) * 4;
  if (i >= n) return;
  float4 v = *(const float4*)(in + i);
  ushort4 o;
  o.x = f2bf(v.x); o.y = f2bf(v.y); o.z = f2bf(v.z); o.w = f2bf(v.w);
  *(ushort4*)(out + i) = o;
}

// ---------------- BT-GEMM: C[m,n] = sum_k A[m,k]*W[n,k] ----------------
// M=8192, N=1024, K=1024 fixed. Tile 128x128, BK=64, 4 waves (2x2).
// MODE 0: bf16 out into [B,H,N,64] layout (q,k)
// MODE 1: fp32 out linear [m*1024+n]     (final)
// MODE 2: bf16 out into [B,H,64,NSEQ] (V transposed)
template <int MODE>
__global__ __launch_bounds__(256) void gemm_bt(const u16* __restrict__ A,
                                               const u16* __restrict__ W,
                                               void* __restrict__ C) {
  __shared__ __align__(16) u16 Al[128 * 64];
  __shared__ __align__(16) u16 Bl[128 * 64];
  const int tid = threadIdx.x;
  const int w = tid >> 6, l = tid & 63;
  const int l15 = l & 15, l4 = l >> 4;
  const int bm = blockIdx.x, bn = blockIdx.y;
  const int wm = w >> 1, wn = w & 1;

  f32x4 acc[4][4] = {};

  for (int ks = 0; ks < 1024; ks += 64) {
    __syncthreads();
#pragma unroll
    for (int c = 0; c < 4; ++c) {
      int g = w * 256 + c * 64 + l;
      int row = g >> 3, gc = g & 7;
      int sgc = gc ^ (row & 7);
      gload_lds16(A + (size_t)(bm * 128 + row) * 1024 + ks + sgc * 8, &Al[g * 8]);
      gload_lds16(W + (size_t)(bn * 128 + row) * 1024 + ks + sgc * 8, &Bl[g * 8]);
    }
    __syncthreads();
#pragma unroll
    for (int kc = 0; kc < 2; ++kc) {
      bf16x8 af[4], bfr[4];
#pragma unroll
      for (int mi = 0; mi < 4; ++mi) {
        int row = wm * 64 + mi * 16 + l15;
        int gc2 = (kc * 4 + l4) ^ (row & 7);
        af[mi] = *(const bf16x8*)&Al[row * 64 + gc2 * 8];
      }
#pragma unroll
      for (int ni = 0; ni < 4; ++ni) {
        int row = wn * 64 + ni * 16 + l15;
        int gc2 = (kc * 4 + l4) ^ (row & 7);
        bfr[ni] = *(const bf16x8*)&Bl[row * 64 + gc2 * 8];
      }
#pragma unroll
      for (int mi = 0; mi < 4; ++mi)
#pragma unroll
        for (int ni = 0; ni < 4; ++ni)
          acc[mi][ni] = __builtin_amdgcn_mfma_f32_16x16x32_bf16(af[mi], bfr[ni],
                                                                acc[mi][ni], 0, 0, 0);
    }
  }

#pragma unroll
  for (int mi = 0; mi < 4; ++mi)
#pragma unroll
    for (int ni = 0; ni < 4; ++ni)
#pragma unroll
      for (int r = 0; r < 4; ++r) {
        int m = bm * 128 + wm * 64 + mi * 16 + l4 * 4 + r;
        int n = bn * 128 + wn * 64 + ni * 16 + l15;
        float val = acc[mi][ni][r];
        if constexpr (MODE == 0) {
          int b = m >> 11, row = m & 2047, h = n >> 6, d = n & 63;
          ((u16*)C)[(((size_t)(b * 16 + h)) * NSEQ + row) * 64 + d] = f2bf(val);
        } else if constexpr (MODE == 1) {
          ((float*)C)[(size_t)m * 1024 + n] = val;
        } else {
          int b = m >> 11, kk = m & 2047, h = n >> 6, d = n & 63;
          ((u16*)C)[(((size_t)(b * 16 + h)) * 64 + d) * NSEQ + kk] = f2bf(val);
        }
      }
}

// ---------------- flash attention ----------------
// grid: (32 qblocks, 64 bh). block 256 (4 waves x 16 q-rows). KT=64.
__global__ __launch_bounds__(256) void attn_kernel(
    const u16* __restrict__ q, const u16* __restrict__ k, const u16* __restrict__ vT,
    const float* __restrict__ alibi, const int* __restrict__ mask,
    u16* __restrict__ o) {
  __shared__ __align__(16) u16 Kl[64 * 64];
  __shared__ __align__(16) u16 Vl[64 * 64];
  __shared__ __align__(16) u16 Pl[4][16 * 64];

  const int tid = threadIdx.x, w = tid >> 6, l = tid & 63;
  const int l15 = l & 15, l4 = l >> 4;
  const int qb = blockIdx.x, bh = blockIdx.y;
  const int b = bh >> 4, h = bh & 15;
  const int wq0 = qb * 64 + w * 16;

  bf16x8 aq[2];
  {
    const u16* qrow = q + ((size_t)bh * NSEQ + wq0 + l15) * 64;
    aq[0] = *(const bf16x8*)(qrow + l4 * 8);
    aq[1] = *(const bf16x8*)(qrow + 32 + l4 * 8);
  }

  f32x4 oacc[4] = {};
  float m_run[4], l_run[4];
#pragma unroll
  for (int r = 0; r < 4; ++r) { m_run[r] = -3.0e38f; l_run[r] = 0.f; }

  const float* al_base = alibi + (size_t)h * NSEQ * NSEQ;
  const int* mk_base = mask + (size_t)b * NSEQ * NSEQ;

  for (int kt = 0; kt < NSEQ; kt += 64) {
    __syncthreads();
#pragma unroll
    for (int c = 0; c < 2; ++c) {
      int g = w * 128 + c * 64 + l;
      int row = g >> 3, gc = g & 7;
      int sgc = gc ^ (row & 7);
      gload_lds16(k + ((size_t)bh * NSEQ + kt + row) * 64 + sgc * 8, &Kl[g * 8]);
      gload_lds16(vT + ((size_t)bh * 64 + row) * NSEQ + kt + sgc * 8, &Vl[g * 8]);
    }
    __syncthreads();

    // S = Q K^T  (16q x 64k per wave)
    f32x4 sacc[4];
#pragma unroll
    for (int kb = 0; kb < 4; ++kb) {
      f32x4 z = {0.f, 0.f, 0.f, 0.f};
      sacc[kb] = z;
#pragma unroll
      for (int dc = 0; dc < 2; ++dc) {
        int row = kb * 16 + l15;
        int gc2 = (dc * 4 + l4) ^ (row & 7);
        bf16x8 bk = *(const bf16x8*)&Kl[row * 64 + gc2 * 8];
        sacc[kb] = __builtin_amdgcn_mfma_f32_16x16x32_bf16(aq[dc], bk, sacc[kb], 0, 0, 0);
      }
    }

    // scale + alibi + mask
    float sv[4][4];
#pragma unroll
    for (int kb = 0; kb < 4; ++kb) {
      int kcol = kt + kb * 16 + l15;
#pragma unroll
      for (int r = 0; r < 4; ++r) {
        int qrow = wq0 + l4 * 4 + r;
        float s = sacc[kb][r] * ATT_SCALE + al_base[(size_t)qrow * NSEQ + kcol];
        if (mk_base[(size_t)qrow * NSEQ + kcol] == 0) s = -3.0e38f;
        sv[kb][r] = s;
      }
    }

    // online softmax (row = q, spread over l15 lanes)
    float tm[4], fac[4];
#pragma unroll
    for (int r = 0; r < 4; ++r)
      tm[r] = fmaxf(fmaxf(sv[0][r], sv[1][r]), fmaxf(sv[2][r], sv[3][r]));
#pragma unroll
    for (int off = 1; off < 16; off <<= 1)
#pragma unroll
      for (int r = 0; r < 4; ++r)
        tm[r] = fmaxf(tm[r], __shfl_xor(tm[r], off));
#pragma unroll
    for (int r = 0; r < 4; ++r) {
      float mn = fmaxf(m_run[r], tm[r]);
      fac[r] = exp2f((m_run[r] - mn) * LOG2E);
      m_run[r] = mn;
      l_run[r] *= fac[r];
    }
#pragma unroll
    for (int db = 0; db < 4; ++db)
#pragma unroll
      for (int r = 0; r < 4; ++r) oacc[db][r] *= fac[r];

    float ts[4] = {0.f, 0.f, 0.f, 0.f};
#pragma unroll
    for (int kb = 0; kb < 4; ++kb)
#pragma unroll
      for (int r = 0; r < 4; ++r) {
        float p = exp2f((sv[kb][r] - m_run[r]) * LOG2E);
        sv[kb][r] = p;
        ts[r] += p;
      }
#pragma unroll
    for (int off = 1; off < 16; off <<= 1)
#pragma unroll
      for (int r = 0; r < 4; ++r) ts[r] += __shfl_xor(ts[r], off);
#pragma unroll
    for (int r = 0; r < 4; ++r) l_run[r] += ts[r];

    // write P (bf16, swizzled) to per-wave LDS
#pragma unroll
    for (int kb = 0; kb < 4; ++kb)
#pragma unroll
      for (int r = 0; r < 4; ++r) {
        int qloc = l4 * 4 + r;
        int col = kb * 16 + l15;
        int gc3 = (col >> 3) ^ (qloc & 7);
        Pl[w][qloc * 64 + gc3 * 8 + (col & 7)] = f2bf(sv[kb][r]);
      }
    asm volatile("s_waitcnt lgkmcnt(0)" ::: "memory");
    __builtin_amdgcn_sched_barrier(0);

    // O += P V
#pragma unroll
    for (int kc = 0; kc < 2; ++kc) {
      int gp = (kc * 4 + l4) ^ (l15 & 7);
      bf16x8 pa = *(const bf16x8*)&Pl[w][l15 * 64 + gp * 8];
#pragma unroll
      for (int db = 0; db < 4; ++db) {
        int row = db * 16 + l15;
        int gv = (kc * 4 + l4) ^ (row & 7);
        bf16x8 bv = *(const bf16x8*)&Vl[row * 64 + gv * 8];
        oacc[db] = __builtin_amdgcn_mfma_f32_16x16x32_bf16(pa, bv, oacc[db], 0, 0, 0);
      }
    }
  }

  // normalize + write O into [B, N, 1024] bf16
#pragma unroll
  for (int db = 0; db < 4; ++db)
#pragma unroll
    for (int r = 0; r < 4; ++r) {
      int qrow = wq0 + l4 * 4 + r;
      int d = db * 16 + l15;
      float val = oacc[db][r] / l_run[r];
      o[((size_t)b * NSEQ + qrow) * DMODEL + h * 64 + d] = f2bf(val);
    }
}

extern "C" void kernel_launch(void* const* d_in, const int* in_sizes, int n_in,
                              void* d_out, int out_size, void* d_ws, size_t ws_size,
                              hipStream_t stream) {
  (void)in_sizes; (void)n_in; (void)out_size; (void)ws_size;
  const float* x = (const float*)d_in[0];
  const int* mask = (const int*)d_in[1];
  const float* alibi = (const float*)d_in[2];
  const float* Wq = (const float*)d_in[3];
  const float* Wk = (const float*)d_in[4];
  const float* Wv = (const float*)d_in[5];
  const float* Wo = (const float*)d_in[6];
  float* out = (float*)d_out;

  char* ws = (char*)d_ws;
  const size_t MB = 1u << 20;
  u16* xb  = (u16*)(ws + 0 * MB);    // 16 MB
  u16* wqb = (u16*)(ws + 16 * MB);   // 2 MB
  u16* wkb = (u16*)(ws + 18 * MB);
  u16* wvb = (u16*)(ws + 20 * MB);
  u16* wob = (u16*)(ws + 22 * MB);
  u16* qb  = (u16*)(ws + 24 * MB);   // 16 MB  [B,H,N,64]
  u16* kb  = (u16*)(ws + 40 * MB);   // 16 MB  [B,H,N,64]
  u16* vT  = (u16*)(ws + 56 * MB);   // 16 MB  [B,H,64,N]
  u16* ob  = (u16*)(ws + 72 * MB);   // 16 MB  [B,N,1024]

  cast_f32_bf16<<<8192, 256, 0, stream>>>(x, xb, MTOT * DMODEL);
  cast_f32_bf16<<<1024, 256, 0, stream>>>(Wq, wqb, DMODEL * DMODEL);
  cast_f32_bf16<<<1024, 256, 0, stream>>>(Wk, wkb, DMODEL * DMODEL);
  cast_f32_bf16<<<1024, 256, 0, stream>>>(Wv, wvb, DMODEL * DMODEL);
  cast_f32_bf16<<<1024, 256, 0, stream>>>(Wo, wob, DMODEL * DMODEL);

  dim3 gg(64, 8), blk(256);
  gemm_bt<0><<<gg, blk, 0, stream>>>(xb, wqb, qb);
  gemm_bt<0><<<gg, blk, 0, stream>>>(xb, wkb, kb);
  gemm_bt<2><<<gg, blk, 0, stream>>>(xb, wvb, vT);

  attn_kernel<<<dim3(32, 64), blk, 0, stream>>>(qb, kb, vT, alibi, mask, ob);

  gemm_bt<1><<<gg, blk, 0, stream>>>(ob, wob, out);
}